// Round 18
// baseline (540.149 us; speedup 1.0000x reference)
//
#include <hip/hip_runtime.h>
#include <hip/hip_bf16.h>
#include <hip/hip_fp16.h>

#define HDIM 1024
#define BATCH 64
#define SEQ 2048
#define MTOT (BATCH*SEQ)   // 131072
#define BM 128
#define BN 256
#define BK 64
#define NKT (HDIM/BK)      // 16 k-tiles
#define NNT (HDIM/BN)      // 4 n-tiles

typedef float f32x4 __attribute__((ext_vector_type(4)));
typedef _Float16 half8 __attribute__((ext_vector_type(8)));
typedef _Float16 half4v __attribute__((ext_vector_type(4)));

static __device__ __forceinline__ void gload_lds16(const void* g, void* l) {
  __builtin_amdgcn_global_load_lds((const __attribute__((address_space(1))) void*)g,
                                   (__attribute__((address_space(3))) void*)l, 16, 0, 0);
}

// ---------------- kernel 1: W1 [h][k] fp32 -> W1T [k][h] fp16 ----------------
__global__ void k_w1t(const float* __restrict__ W1, unsigned short* __restrict__ W1T) {
  __shared__ float tile[64][65];
  int h0 = blockIdx.x * 64, k0 = blockIdx.y * 64;
  int t = threadIdx.x;
#pragma unroll
  for (int j = 0; j < 4; ++j) {
    int q = j * 256 + t, r = q >> 4, c = (q & 15) * 4;
    float4 v = *(const float4*)(W1 + (size_t)(h0 + r) * HDIM + k0 + c);
    tile[r][c + 0] = v.x; tile[r][c + 1] = v.y; tile[r][c + 2] = v.z; tile[r][c + 3] = v.w;
  }
  __syncthreads();
#pragma unroll
  for (int j = 0; j < 4; ++j) {
    int q = j * 256 + t, r = q >> 4, c = (q & 15) * 4;
    union { _Float16 h[4]; ushort4 u; } cv;
    cv.h[0] = (_Float16)tile[c + 0][r];
    cv.h[1] = (_Float16)tile[c + 1][r];
    cv.h[2] = (_Float16)tile[c + 2][r];
    cv.h[3] = (_Float16)tile[c + 3][r];
    *(ushort4*)(W1T + (size_t)(k0 + r) * HDIM + h0 + c) = cv.u;
  }
}

// ---------------- kernel 2: dec_proj = dh @ W2 + b  (fp32, W2 read ONCE) ----------------
// Old structure: 64 blocks x full 4MB W2 = 256MB L2/L3 traffic (~10-25us for a
// 134-MFLOP GEMV). New: 64 blocks each own 16 k-cols -> W2 read once total
// (4MB). dh staged in padded LDS chunks (transposed: broadcast reads, 0-conflict).
// Same h-ascending summation order -> bit-identical dp.
#define DP_CH 128
__global__ void k_decproj(const float* __restrict__ dh, const float* __restrict__ W2,
                          const float* __restrict__ W2b, float* __restrict__ dp) {
  __shared__ float dhs[DP_CH][65];   // [h-in-chunk][b], pad 65 (bank-spread)
  int kc = blockIdx.x;               // 0..63
  int t = threadIdx.x;               // 256 threads
  int k = kc * 16 + (t & 15);
  int bg = t >> 4;                   // 0..15 ; handles b = bg*4 .. bg*4+3
  float acc[4] = {0.f, 0.f, 0.f, 0.f};

  for (int h0 = 0; h0 < HDIM; h0 += DP_CH) {
    __syncthreads();                 // previous chunk's readers done
    // stage dh[0:64][h0:h0+128] -> dhs[h][b] (coalesced float4 global reads)
#pragma unroll
    for (int it = 0; it < 8; ++it) {
      int idx = it * 256 + t;        // 0..2047 quads
      int b = idx >> 5;              // 0..63
      int c4 = (idx & 31) * 4;       // 0..124
      float4 v = *(const float4*)(dh + (size_t)b * HDIM + h0 + c4);
      dhs[c4 + 0][b] = v.x;
      dhs[c4 + 1][b] = v.y;
      dhs[c4 + 2][b] = v.z;
      dhs[c4 + 3][b] = v.w;
    }
    __syncthreads();
#pragma unroll 4
    for (int hh = 0; hh < DP_CH; ++hh) {
      float w = W2[(size_t)(h0 + hh) * HDIM + k];   // 64B/wave, L1-broadcast
#pragma unroll
      for (int bi = 0; bi < 4; ++bi)
        acc[bi] += dhs[hh][bg * 4 + bi] * w;        // broadcast within 16-lane grp
    }
  }
  float bv = W2b[k];
#pragma unroll
  for (int bi = 0; bi < 4; ++bi)
    dp[(size_t)(bg * 4 + bi) * HDIM + k] = acc[bi] + bv;
}

// ---------------- kernel 3: fused GEMM + tanh + v-dot -> score partials ----------------
// R17 VERBATIM (k_scores is closed: 2-phase plateau 360us pure / 400us with
// E16; 5 scheduling-structure attempts all regressed, m232 regime-gate).
__global__ __launch_bounds__(512, 4) void k_scores(
    const float* __restrict__ E, const unsigned short* __restrict__ W1T,
    const float* __restrict__ W1b, const float* __restrict__ dp,
    const float* __restrict__ vw, float* __restrict__ spart,
    unsigned short* __restrict__ E16, int we16) {
  __shared__ __align__(16) _Float16 As[BM * BK];         // 16384 B, swizzled
  __shared__ __align__(16) unsigned short Bs[BN * BK];   // 32768 B, swizzled
  float (*scr)[4] = (float(*)[4])As;                     // epilogue alias (post-barrier safe)

  int t = threadIdx.x;
  int bid = blockIdx.x;                 // 0..4095
  int xcd = bid & 7;
  int q = bid >> 3;                     // 0..511
  int mt = (xcd << 7) + (q >> 2);       // 128 m-tiles per XCD
  int nt = q & 3;
  int m0 = mt * BM, n0 = nt * BN;
  int b = m0 >> 11;

  int lane = t & 63, wid = t >> 6;
  int wr = wid >> 2, wc = wid & 3;
  int l15 = lane & 15, l4 = lane >> 4;

  f32x4 acc[4][4];
#pragma unroll
  for (int i = 0; i < 4; ++i)
#pragma unroll
    for (int j = 0; j < 4; ++j) acc[i][j] = {0.f, 0.f, 0.f, 0.f};

  int ar = t >> 4;                       // 0..31 ; row&7 == ar&7
  int ac = (t & 15) * 4;                 // 0..60
  int aswz = (((ac >> 3) ^ (ar & 7)) << 4) + ((ac & 7) << 1);
  const float* Ab = E + (size_t)m0 * HDIM;
  unsigned short* e16p = E16 + (size_t)(m0 + nt * 32 + ar) * HDIM + ac;

  float4 areg[4];
#pragma unroll
  for (int j = 0; j < 4; ++j)
    areg[j] = *(const float4*)(Ab + (size_t)(j * 32 + ar) * HDIM + ac);

  for (int kt = 0; kt < NKT; ++kt) {
#pragma unroll
    for (int j = 0; j < 4; ++j) {
      int chunk = wid * 4 + j;
      int row = chunk * 8 + (lane >> 3);
      int u = (lane & 7) ^ (lane >> 3);
      const unsigned short* g = W1T + (size_t)(n0 + row) * HDIM + kt * BK + u * 8;
      gload_lds16(g, (char*)Bs + (size_t)chunk * 1024);
    }

    unsigned long long e16v = 0;
#pragma unroll
    for (int j = 0; j < 4; ++j) {
      union { _Float16 h[4]; unsigned long long u64; } cv;
      cv.h[0] = (_Float16)areg[j].x; cv.h[1] = (_Float16)areg[j].y;
      cv.h[2] = (_Float16)areg[j].z; cv.h[3] = (_Float16)areg[j].w;
      *(unsigned long long*)((char*)As + (j * 32 + ar) * 128 + aswz) = cv.u64;
      if (j == nt) e16v = cv.u64;
    }

    __syncthreads();

    if (we16)
      __builtin_nontemporal_store(e16v, (unsigned long long*)(e16p + kt * BK));

    int ktn = ((kt + 1) & (NKT - 1)) * BK;
#pragma unroll
    for (int j = 0; j < 4; ++j)
      areg[j] = *(const float4*)(Ab + (size_t)(j * 32 + ar) * HDIM + ktn + ac);

    __builtin_amdgcn_s_setprio(1);
#pragma unroll
    for (int ks = 0; ks < 2; ++ks) {
      half8 af[4], bf[4];
#pragma unroll
      for (int mi = 0; mi < 4; ++mi) {
        int row = wr * 64 + mi * 16 + l15;
        af[mi] = *(const half8*)((const char*)As + row * 128 + (((ks * 4 + l4) ^ (row & 7)) << 4));
      }
#pragma unroll
      for (int ni = 0; ni < 4; ++ni) {
        int row = wc * 64 + ni * 16 + l15;
        bf[ni] = *(const half8*)((const char*)Bs + row * 128 + (((ks * 4 + l4) ^ (row & 7)) << 4));
      }
#pragma unroll
      for (int mi = 0; mi < 4; ++mi)
#pragma unroll
        for (int ni = 0; ni < 4; ++ni)
          acc[mi][ni] = __builtin_amdgcn_mfma_f32_16x16x32_f16(af[mi], bf[ni], acc[mi][ni], 0, 0, 0);
    }
    __builtin_amdgcn_s_setprio(0);

    __syncthreads();
  }

  float bias_l[4], v_l[4];
#pragma unroll
  for (int ni = 0; ni < 4; ++ni) {
    int k = n0 + wc * 64 + ni * 16 + l15;
    bias_l[ni] = W1b[k] + dp[(size_t)b * HDIM + k];
    v_l[ni] = vw[k];
  }
#pragma unroll
  for (int mi = 0; mi < 4; ++mi) {
#pragma unroll
    for (int r = 0; r < 4; ++r) {
      float s = 0.f;
#pragma unroll
      for (int ni = 0; ni < 4; ++ni) {
        float x = acc[mi][ni][r] + bias_l[ni];
        float ex = __expf(2.f * x);
        float th = 1.f - 2.f / (ex + 1.f);
        s += th * v_l[ni];
      }
      s += __shfl_xor(s, 1); s += __shfl_xor(s, 2);
      s += __shfl_xor(s, 4); s += __shfl_xor(s, 8);
      if (l15 == 0) scr[wr * 64 + mi * 16 + l4 * 4 + r][wc] = s;
    }
  }
  __syncthreads();
  if (t < BM) {
    f32x4 p = *(const f32x4*)scr[t];
    spart[((size_t)m0 + t) * NNT + nt] = (p[0] + p[1]) + (p[2] + p[3]);
  }
}

// ---------------- kernel 4: softmax over S per batch ----------------
__global__ void k_softmax(const float* __restrict__ spart, float* __restrict__ attn) {
  __shared__ float sc[SEQ];
  __shared__ float red[8];
  int b = blockIdx.x, t = threadIdx.x;
  float mx = -1e30f;
#pragma unroll
  for (int j = 0; j < 8; ++j) {
    int s = j * 256 + t;
    f32x4 x = *(const f32x4*)(spart + ((size_t)b * SEQ + s) * NNT);
    float v = (x[0] + x[1]) + (x[2] + x[3]);
    sc[s] = v;
    mx = fmaxf(mx, v);
  }
  for (int m = 1; m < 64; m <<= 1) mx = fmaxf(mx, __shfl_xor(mx, m));
  if ((t & 63) == 0) red[t >> 6] = mx;
  __syncthreads();
  mx = fmaxf(fmaxf(red[0], red[1]), fmaxf(red[2], red[3]));
  float w[8]; float sum = 0.f;
#pragma unroll
  for (int j = 0; j < 8; ++j) {
    float e = __expf(sc[j * 256 + t] - mx);
    w[j] = e; sum += e;
  }
  for (int m = 1; m < 64; m <<= 1) sum += __shfl_xor(sum, m);
  if ((t & 63) == 0) red[4 + (t >> 6)] = sum;
  __syncthreads();
  float inv = 1.f / (red[4] + red[5] + red[6] + red[7]);
#pragma unroll
  for (int j = 0; j < 8; ++j)
    attn[(size_t)b * SEQ + j * 256 + t] = w[j] * inv;
}

// ---------------- kernel 5a: context partials, fp32 E (fallback) ----------------
__global__ void k_ctx_part(const float* __restrict__ E, const float* __restrict__ attn,
                           float* __restrict__ cpart, int rpc) {
  int b = blockIdx.y, ch = blockIdx.x, nch = gridDim.x;
  int t = threadIdx.x;
  const float* wrow = attn + (size_t)b * SEQ + (size_t)ch * rpc;
  const float* Eb = E + ((size_t)b * SEQ + (size_t)ch * rpc) * HDIM;
  f32x4 acc = {0.f, 0.f, 0.f, 0.f};
#pragma unroll 4
  for (int s = 0; s < rpc; ++s) {
    float w = wrow[s];
    f32x4 e = *(const f32x4*)(Eb + (size_t)s * HDIM + t * 4);
    acc += e * w;
  }
  *(f32x4*)(cpart + ((size_t)b * nch + ch) * HDIM + t * 4) = acc;
}

// ---------------- kernel 5b: context partials, fp16 E mirror (half the bytes) ----------------
__global__ void k_ctx_part16(const unsigned short* __restrict__ E16, const float* __restrict__ attn,
                             float* __restrict__ cpart, int rpc) {
  int b = blockIdx.y, ch = blockIdx.x, nch = gridDim.x;
  int t = threadIdx.x;
  const float* wrow = attn + (size_t)b * SEQ + (size_t)ch * rpc;
  const unsigned short* Eb = E16 + ((size_t)b * SEQ + (size_t)ch * rpc) * HDIM;
  f32x4 acc = {0.f, 0.f, 0.f, 0.f};
#pragma unroll 4
  for (int s = 0; s < rpc; ++s) {
    float w = wrow[s];
    half4v e = *(const half4v*)(Eb + (size_t)s * HDIM + t * 4);
    acc[0] += w * (float)e[0];
    acc[1] += w * (float)e[1];
    acc[2] += w * (float)e[2];
    acc[3] += w * (float)e[3];
  }
  *(f32x4*)(cpart + ((size_t)b * nch + ch) * HDIM + t * 4) = acc;
}

// ---------------- kernel 6: reduce context partials ----------------
__global__ void k_ctx_reduce(const float* __restrict__ cpart, float* __restrict__ ctx, int nch) {
  int idx = blockIdx.x * 256 + threadIdx.x;  // 0..65535
  int b = idx >> 10, k = idx & 1023;
  float s = 0.f;
  for (int c = 0; c < nch; ++c) s += cpart[((size_t)(b * nch + c)) * HDIM + k];
  ctx[idx] = s;
}

extern "C" void kernel_launch(void* const* d_in, const int* in_sizes, int n_in,
                              void* d_out, int out_size, void* d_ws, size_t ws_size,
                              hipStream_t stream) {
  const float* dh  = (const float*)d_in[0];
  const float* E   = (const float*)d_in[1];
  const float* W1w = (const float*)d_in[2];
  const float* W1b = (const float*)d_in[3];
  const float* W2w = (const float*)d_in[4];
  const float* W2b = (const float*)d_in[5];
  const float* vw  = (const float*)d_in[6];
  float* out  = (float*)d_out;
  float* ctx  = out;                 // [64,1024]
  float* attn = out + BATCH * HDIM;  // [64,2048]

  char* ws = (char*)d_ws;
  unsigned short* W1T = (unsigned short*)ws;                 // 2 MB
  float* dp    = (float*)(ws + (2u << 20));                  // 256 KB
  float* spart = (float*)(ws + (2u << 20) + (256u << 10));   // 2 MB used (4 MB reserved)
  float* cpart = (float*)(ws + (6u << 20) + (256u << 10));   // up to 8 MB
  unsigned short* E16 = (unsigned short*)(ws + (14u << 20) + (256u << 10));  // 256 MB if it fits

  size_t need32  = (6u << 20) + (256u << 10) + (size_t)BATCH * 32 * HDIM * 4;
  size_t needE16 = (14u << 20) + (256u << 10) + (size_t)MTOT * HDIM * 2;
  int nch = (ws_size >= need32) ? 32 : 16;
  int rpc = SEQ / nch;
  int use16 = (ws_size >= needE16) ? 1 : 0;

  k_w1t<<<dim3(16, 16), 256, 0, stream>>>(W1w, W1T);
  k_decproj<<<64, 256, 0, stream>>>(dh, W2w, W2b, dp);
  k_scores<<<(MTOT / BM) * NNT, 512, 0, stream>>>(E, W1T, W1b, dp, vw, spart,
                                                  use16 ? E16 : W1T, use16);
  k_softmax<<<BATCH, 256, 0, stream>>>(spart, attn);
  if (use16)
    k_ctx_part16<<<dim3(nch, BATCH), 256, 0, stream>>>(E16, attn, cpart, rpc);
  else
    k_ctx_part<<<dim3(nch, BATCH), 256, 0, stream>>>(E, attn, cpart, rpc);
  k_ctx_reduce<<<256, 256, 0, stream>>>(cpart, ctx, nch);
}

// Round 19
// 503.251 us; speedup vs baseline: 1.0733x; 1.0733x over previous
//
#include <hip/hip_runtime.h>
#include <hip/hip_bf16.h>
#include <hip/hip_fp16.h>

#define HDIM 1024
#define BATCH 64
#define SEQ 2048
#define MTOT (BATCH*SEQ)   // 131072
#define BM 128
#define BN 256
#define BK 64
#define NKT (HDIM/BK)      // 16 k-tiles
#define NNT (HDIM/BN)      // 4 n-tiles

typedef float f32x4 __attribute__((ext_vector_type(4)));
typedef _Float16 half8 __attribute__((ext_vector_type(8)));
typedef _Float16 half4v __attribute__((ext_vector_type(4)));

static __device__ __forceinline__ void gload_lds16(const void* g, void* l) {
  __builtin_amdgcn_global_load_lds((const __attribute__((address_space(1))) void*)g,
                                   (__attribute__((address_space(3))) void*)l, 16, 0, 0);
}

// ---------------- kernel 1: W1 [h][k] fp32 -> W1T [k][h] fp16 ----------------
__global__ void k_w1t(const float* __restrict__ W1, unsigned short* __restrict__ W1T) {
  __shared__ float tile[64][65];
  int h0 = blockIdx.x * 64, k0 = blockIdx.y * 64;
  int t = threadIdx.x;
#pragma unroll
  for (int j = 0; j < 4; ++j) {
    int q = j * 256 + t, r = q >> 4, c = (q & 15) * 4;
    float4 v = *(const float4*)(W1 + (size_t)(h0 + r) * HDIM + k0 + c);
    tile[r][c + 0] = v.x; tile[r][c + 1] = v.y; tile[r][c + 2] = v.z; tile[r][c + 3] = v.w;
  }
  __syncthreads();
#pragma unroll
  for (int j = 0; j < 4; ++j) {
    int q = j * 256 + t, r = q >> 4, c = (q & 15) * 4;
    union { _Float16 h[4]; ushort4 u; } cv;
    cv.h[0] = (_Float16)tile[c + 0][r];
    cv.h[1] = (_Float16)tile[c + 1][r];
    cv.h[2] = (_Float16)tile[c + 2][r];
    cv.h[3] = (_Float16)tile[c + 3][r];
    *(ushort4*)(W1T + (size_t)(k0 + r) * HDIM + h0 + c) = cv.u;
  }
}

// ---------------- kernel 2: dec_proj = dh @ W2 + b  (fp32) ----------------
// R17 version restored: streaming W2 coalesced is L2-resident after first
// touch per XCD (32MB HBM total) and latency-hidden -> already at its floor.
// R18's "W2 read once" restructure was latency-bound (scalar LDS inner loop,
// 64 blocks = 1/4 of CUs) and regressed.
__global__ void k_decproj(const float* __restrict__ dh, const float* __restrict__ W2,
                          const float* __restrict__ W2b, float* __restrict__ dp) {
  __shared__ float drow[HDIM];
  int b = blockIdx.x, t = threadIdx.x;
#pragma unroll
  for (int j = 0; j < 4; ++j) drow[j * 256 + t] = dh[(size_t)b * HDIM + j * 256 + t];
  __syncthreads();
  f32x4 acc = {0.f, 0.f, 0.f, 0.f};
#pragma unroll 16
  for (int h = 0; h < HDIM; ++h) {
    float d = drow[h];
    f32x4 w = *(const f32x4*)(W2 + (size_t)h * HDIM + t * 4);
    acc += w * d;
  }
  acc += *(const f32x4*)(W2b + t * 4);
  *(f32x4*)(dp + (size_t)b * HDIM + t * 4) = acc;
}

// ---------------- kernel 3: fused GEMM + tanh + v-dot -> score partials ----------------
// R17 VERBATIM — the session's best (503us total). 2-phase plateau: 360us pure
// / ~400us with E16 side-write. All scheduling restructures (R7/R10/R13/R16)
// regressed (m232 regime-gate at this tile shape); k_scores is closed.
__global__ __launch_bounds__(512, 4) void k_scores(
    const float* __restrict__ E, const unsigned short* __restrict__ W1T,
    const float* __restrict__ W1b, const float* __restrict__ dp,
    const float* __restrict__ vw, float* __restrict__ spart,
    unsigned short* __restrict__ E16, int we16) {
  __shared__ __align__(16) _Float16 As[BM * BK];         // 16384 B, swizzled
  __shared__ __align__(16) unsigned short Bs[BN * BK];   // 32768 B, swizzled
  float (*scr)[4] = (float(*)[4])As;                     // epilogue alias (post-barrier safe)

  int t = threadIdx.x;
  // XCD-aware remap: all 4 n-tiles of an m-tile adjacent on one XCD.
  int bid = blockIdx.x;                 // 0..4095
  int xcd = bid & 7;
  int q = bid >> 3;                     // 0..511
  int mt = (xcd << 7) + (q >> 2);       // 128 m-tiles per XCD
  int nt = q & 3;
  int m0 = mt * BM, n0 = nt * BN;
  int b = m0 >> 11;

  int lane = t & 63, wid = t >> 6;      // 8 waves: wr = row-half, wc = col-quarter
  int wr = wid >> 2, wc = wid & 3;
  int l15 = lane & 15, l4 = lane >> 4;

  f32x4 acc[4][4];
#pragma unroll
  for (int i = 0; i < 4; ++i)
#pragma unroll
    for (int j = 0; j < 4; ++j) acc[i][j] = {0.f, 0.f, 0.f, 0.f};

  // A staging coords: 512 thr cover 128x64 fp32 as 4 float4/thread.
  int ar = t >> 4;                       // 0..31 ; row&7 == ar&7
  int ac = (t & 15) * 4;                 // 0..60
  int aswz = (((ac >> 3) ^ (ar & 7)) << 4) + ((ac & 7) << 1);
  const float* Ab = E + (size_t)m0 * HDIM;
  unsigned short* e16p = E16 + (size_t)(m0 + nt * 32 + ar) * HDIM + ac;  // this block's slice

  // prologue: A(0) -> regs
  float4 areg[4];
#pragma unroll
  for (int j = 0; j < 4; ++j)
    areg[j] = *(const float4*)(Ab + (size_t)(j * 32 + ar) * HDIM + ac);

  for (int kt = 0; kt < NKT; ++kt) {
    // (1) issue B(kt): 4 gload_lds per wave (32 chunks of 1KB), pre-swizzled src.
#pragma unroll
    for (int j = 0; j < 4; ++j) {
      int chunk = wid * 4 + j;                     // 0..31 (wave-uniform)
      int row = chunk * 8 + (lane >> 3);           // 0..255 ; row&7 == lane>>3
      int u = (lane & 7) ^ (lane >> 3);
      const unsigned short* g = W1T + (size_t)(n0 + row) * HDIM + kt * BK + u * 8;
      gload_lds16(g, (char*)Bs + (size_t)chunk * 1024);
    }

    // (2) cvt A(kt) regs -> fp16 -> swizzled LDS; capture j==nt slice in a reg
    unsigned long long e16v = 0;
#pragma unroll
    for (int j = 0; j < 4; ++j) {
      union { _Float16 h[4]; unsigned long long u64; } cv;
      cv.h[0] = (_Float16)areg[j].x; cv.h[1] = (_Float16)areg[j].y;
      cv.h[2] = (_Float16)areg[j].z; cv.h[3] = (_Float16)areg[j].w;
      *(unsigned long long*)((char*)As + (j * 32 + ar) * 128 + aswz) = cv.u64;
      if (j == nt) e16v = cv.u64;
    }

    __syncthreads();   // drains B gloads + A ds_writes (no store ack here)

    // (3) E16 store issued AFTER barrier #1: ack drains at barrier #2, covered
    //     by the MFMA phase. Nontemporal -> no L2 eviction of the working set.
    if (we16)
      __builtin_nontemporal_store(e16v, (unsigned long long*)(e16p + kt * BK));

    //     prefetch A(kt+1) -> regs; latency hides under MFMA below
    int ktn = ((kt + 1) & (NKT - 1)) * BK;
#pragma unroll
    for (int j = 0; j < 4; ++j)
      areg[j] = *(const float4*)(Ab + (size_t)(j * 32 + ar) * HDIM + ktn + ac);

    // (4) fragments + MFMA (swizzled reads: 0 conflicts)
    __builtin_amdgcn_s_setprio(1);
#pragma unroll
    for (int ks = 0; ks < 2; ++ks) {
      half8 af[4], bf[4];
#pragma unroll
      for (int mi = 0; mi < 4; ++mi) {
        int row = wr * 64 + mi * 16 + l15;
        af[mi] = *(const half8*)((const char*)As + row * 128 + (((ks * 4 + l4) ^ (row & 7)) << 4));
      }
#pragma unroll
      for (int ni = 0; ni < 4; ++ni) {
        int row = wc * 64 + ni * 16 + l15;
        bf[ni] = *(const half8*)((const char*)Bs + row * 128 + (((ks * 4 + l4) ^ (row & 7)) << 4));
      }
#pragma unroll
      for (int mi = 0; mi < 4; ++mi)
#pragma unroll
        for (int ni = 0; ni < 4; ++ni)
          acc[mi][ni] = __builtin_amdgcn_mfma_f32_16x16x32_f16(af[mi], bf[ni], acc[mi][ni], 0, 0, 0);
    }
    __builtin_amdgcn_s_setprio(0);

    __syncthreads();   // LDS reads done before next iter overwrites
  }

  // epilogue: bias/v loaded here (VGPR headroom during loop)
  float bias_l[4], v_l[4];
#pragma unroll
  for (int ni = 0; ni < 4; ++ni) {
    int k = n0 + wc * 64 + ni * 16 + l15;
    bias_l[ni] = W1b[k] + dp[(size_t)b * HDIM + k];
    v_l[ni] = vw[k];
  }
#pragma unroll
  for (int mi = 0; mi < 4; ++mi) {
#pragma unroll
    for (int r = 0; r < 4; ++r) {
      float s = 0.f;
#pragma unroll
      for (int ni = 0; ni < 4; ++ni) {
        float x = acc[mi][ni][r] + bias_l[ni];
        float ex = __expf(2.f * x);
        float th = 1.f - 2.f / (ex + 1.f);
        s += th * v_l[ni];
      }
      s += __shfl_xor(s, 1); s += __shfl_xor(s, 2);
      s += __shfl_xor(s, 4); s += __shfl_xor(s, 8);
      if (l15 == 0) scr[wr * 64 + mi * 16 + l4 * 4 + r][wc] = s;
    }
  }
  __syncthreads();
  if (t < BM) {
    f32x4 p = *(const f32x4*)scr[t];
    spart[((size_t)m0 + t) * NNT + nt] = (p[0] + p[1]) + (p[2] + p[3]);
  }
}

// ---------------- kernel 4: softmax over S per batch ----------------
__global__ void k_softmax(const float* __restrict__ spart, float* __restrict__ attn) {
  __shared__ float sc[SEQ];
  __shared__ float red[8];
  int b = blockIdx.x, t = threadIdx.x;
  float mx = -1e30f;
#pragma unroll
  for (int j = 0; j < 8; ++j) {
    int s = j * 256 + t;
    f32x4 x = *(const f32x4*)(spart + ((size_t)b * SEQ + s) * NNT);
    float v = (x[0] + x[1]) + (x[2] + x[3]);
    sc[s] = v;
    mx = fmaxf(mx, v);
  }
  for (int m = 1; m < 64; m <<= 1) mx = fmaxf(mx, __shfl_xor(mx, m));
  if ((t & 63) == 0) red[t >> 6] = mx;
  __syncthreads();
  mx = fmaxf(fmaxf(red[0], red[1]), fmaxf(red[2], red[3]));
  float w[8]; float sum = 0.f;
#pragma unroll
  for (int j = 0; j < 8; ++j) {
    float e = __expf(sc[j * 256 + t] - mx);
    w[j] = e; sum += e;
  }
  for (int m = 1; m < 64; m <<= 1) sum += __shfl_xor(sum, m);
  if ((t & 63) == 0) red[4 + (t >> 6)] = sum;
  __syncthreads();
  float inv = 1.f / (red[4] + red[5] + red[6] + red[7]);
#pragma unroll
  for (int j = 0; j < 8; ++j)
    attn[(size_t)b * SEQ + j * 256 + t] = w[j] * inv;
}

// ---------------- kernel 5a: context partials, fp32 E (fallback) ----------------
__global__ void k_ctx_part(const float* __restrict__ E, const float* __restrict__ attn,
                           float* __restrict__ cpart, int rpc) {
  int b = blockIdx.y, ch = blockIdx.x, nch = gridDim.x;
  int t = threadIdx.x;
  const float* wrow = attn + (size_t)b * SEQ + (size_t)ch * rpc;
  const float* Eb = E + ((size_t)b * SEQ + (size_t)ch * rpc) * HDIM;
  f32x4 acc = {0.f, 0.f, 0.f, 0.f};
#pragma unroll 4
  for (int s = 0; s < rpc; ++s) {
    float w = wrow[s];
    f32x4 e = *(const f32x4*)(Eb + (size_t)s * HDIM + t * 4);
    acc += e * w;
  }
  *(f32x4*)(cpart + ((size_t)b * nch + ch) * HDIM + t * 4) = acc;
}

// ---------------- kernel 5b: context partials, fp16 E mirror (half the bytes) ----------------
__global__ void k_ctx_part16(const unsigned short* __restrict__ E16, const float* __restrict__ attn,
                             float* __restrict__ cpart, int rpc) {
  int b = blockIdx.y, ch = blockIdx.x, nch = gridDim.x;
  int t = threadIdx.x;
  const float* wrow = attn + (size_t)b * SEQ + (size_t)ch * rpc;
  const unsigned short* Eb = E16 + ((size_t)b * SEQ + (size_t)ch * rpc) * HDIM;
  f32x4 acc = {0.f, 0.f, 0.f, 0.f};
#pragma unroll 4
  for (int s = 0; s < rpc; ++s) {
    float w = wrow[s];
    half4v e = *(const half4v*)(Eb + (size_t)s * HDIM + t * 4);
    acc[0] += w * (float)e[0];
    acc[1] += w * (float)e[1];
    acc[2] += w * (float)e[2];
    acc[3] += w * (float)e[3];
  }
  *(f32x4*)(cpart + ((size_t)b * nch + ch) * HDIM + t * 4) = acc;
}

// ---------------- kernel 6: reduce context partials ----------------
__global__ void k_ctx_reduce(const float* __restrict__ cpart, float* __restrict__ ctx, int nch) {
  int idx = blockIdx.x * 256 + threadIdx.x;  // 0..65535
  int b = idx >> 10, k = idx & 1023;
  float s = 0.f;
  for (int c = 0; c < nch; ++c) s += cpart[((size_t)(b * nch + c)) * HDIM + k];
  ctx[idx] = s;
}

extern "C" void kernel_launch(void* const* d_in, const int* in_sizes, int n_in,
                              void* d_out, int out_size, void* d_ws, size_t ws_size,
                              hipStream_t stream) {
  const float* dh  = (const float*)d_in[0];
  const float* E   = (const float*)d_in[1];
  const float* W1w = (const float*)d_in[2];
  const float* W1b = (const float*)d_in[3];
  const float* W2w = (const float*)d_in[4];
  const float* W2b = (const float*)d_in[5];
  const float* vw  = (const float*)d_in[6];
  float* out  = (float*)d_out;
  float* ctx  = out;                 // [64,1024]
  float* attn = out + BATCH * HDIM;  // [64,2048]

  char* ws = (char*)d_ws;
  unsigned short* W1T = (unsigned short*)ws;                 // 2 MB
  float* dp    = (float*)(ws + (2u << 20));                  // 256 KB
  float* spart = (float*)(ws + (2u << 20) + (256u << 10));   // 2 MB used (4 MB reserved)
  float* cpart = (float*)(ws + (6u << 20) + (256u << 10));   // up to 8 MB
  unsigned short* E16 = (unsigned short*)(ws + (14u << 20) + (256u << 10));  // 256 MB if it fits

  size_t need32  = (6u << 20) + (256u << 10) + (size_t)BATCH * 32 * HDIM * 4;
  size_t needE16 = (14u << 20) + (256u << 10) + (size_t)MTOT * HDIM * 2;
  int nch = (ws_size >= need32) ? 32 : 16;
  int rpc = SEQ / nch;
  int use16 = (ws_size >= needE16) ? 1 : 0;

  k_w1t<<<dim3(16, 16), 256, 0, stream>>>(W1w, W1T);
  k_decproj<<<BATCH, 256, 0, stream>>>(dh, W2w, W2b, dp);
  k_scores<<<(MTOT / BM) * NNT, 512, 0, stream>>>(E, W1T, W1b, dp, vw, spart,
                                                  use16 ? E16 : W1T, use16);
  k_softmax<<<BATCH, 256, 0, stream>>>(spart, attn);
  if (use16)
    k_ctx_part16<<<dim3(nch, BATCH), 256, 0, stream>>>(E16, attn, cpart, rpc);
  else
    k_ctx_part<<<dim3(nch, BATCH), 256, 0, stream>>>(E, attn, cpart, rpc);
  k_ctx_reduce<<<256, 256, 0, stream>>>(cpart, ctx, nch);
}